// Round 15
// baseline (203.764 us; speedup 1.0000x reference)
//
#include <hip/hip_runtime.h>
#include <hip/hip_bf16.h>

#define BB 64
#define JJ 32
#define NN 4096
#define QD 130
#define KD 128
#define VD 130
#define HH 4
#define CT 8
#define NCH (NN / CT)                 // 512
#define TIL (NCH / 32)                // 16
#define PSTRIDE (JJ + JJ + JJ * VD)   // 4224 floats per partial block

typedef __attribute__((ext_vector_type(8))) __bf16 bf16x8;
typedef __attribute__((ext_vector_type(4))) float  f32x4;

union FW4 { unsigned int u[4]; bf16x8 v; };

#define SEL_HI 0x07060302u

__device__ __forceinline__ unsigned int packhi(float f0, float f1) {
    return __builtin_amdgcn_perm(__float_as_uint(f1), __float_as_uint(f0), SEL_HI);
}
__device__ __forceinline__ float truncbf(float f) {
    return __uint_as_float(__float_as_uint(f) & 0xFFFF0000u);
}
// truncation split: 8 floats -> hi/lo bf16x8 planes (f = h + l + O(2^-17))
__device__ __forceinline__ void split8(float4 a, float4 b, bf16x8* h, bf16x8* l) {
    FW4 H, L;
    H.u[0] = packhi(a.x, a.y);
    H.u[1] = packhi(a.z, a.w);
    H.u[2] = packhi(b.x, b.y);
    H.u[3] = packhi(b.z, b.w);
    L.u[0] = packhi(a.x - truncbf(a.x), a.y - truncbf(a.y));
    L.u[1] = packhi(a.z - truncbf(a.z), a.w - truncbf(a.w));
    L.u[2] = packhi(b.x - truncbf(b.x), b.y - truncbf(b.y));
    L.u[3] = packhi(b.z - truncbf(b.z), b.w - truncbf(b.w));
    *h = H.v; *l = L.v;
}

// Barrier with LDS-visibility only — does NOT drain vmcnt; in-flight global
// prefetch loads (register destinations, compiler-counted vmcnt at their
// consumer) survive across it (T4 in register form). sched_barrier(0)
// fences against hoisting (rule #18).
__device__ __forceinline__ void barrier_novm() {
    __builtin_amdgcn_sched_barrier(0);
    asm volatile("s_waitcnt lgkmcnt(0)" ::: "memory");
    __builtin_amdgcn_s_barrier();
    __builtin_amdgcn_sched_barrier(0);
}

// ---------------------------------------------------------------- encoder ---
__global__ __launch_bounds__(64) void enc_kernel(
        const float* __restrict__ jq,
        const float* __restrict__ W1, const float* __restrict__ b1,
        const float* __restrict__ W2, const float* __restrict__ b2,
        float* __restrict__ qenc) {
    int row = blockIdx.x;          // b*J + j
    int t = threadIdx.x;           // 0..63
    __shared__ float x[QD];
    __shared__ float h[64];
    for (int i = t; i < QD; i += 64) x[i] = jq[row * QD + i];
    __syncthreads();
    float a0 = 0.f, a1 = 0.f;
    for (int i = 0; i < QD - 1; i += 2) {
        a0 += x[i] * W1[i * 64 + t];
        a1 += x[i + 1] * W1[(i + 1) * 64 + t];
    }
    h[t] = fmaxf(b1[t] + a0 + a1, 0.f);
    __syncthreads();
    float a[8];
    #pragma unroll
    for (int s = 0; s < 8; ++s) a[s] = b2[t + 64 * s];
    for (int i = 0; i < 64; ++i) {
        float hv = h[i];
        #pragma unroll
        for (int s = 0; s < 8; ++s) a[s] += hv * W2[i * 512 + t + 64 * s];
    }
    #pragma unroll
    for (int s = 0; s < 8; ++s) qenc[row * 512 + t + 64 * s] = a[s];
}

// -------------------------------------------------------------- attention ---
// Block = (b, chunk of 512 keys), 512 threads = 8 waves = 4 heads x 2
// q-halves. 16x16x32 MFMA; key-permuted K layout so P->A-frag exchange is
// 4 shfl_xor(32). V single-buffered (2-barrier schedule), Kf [65]-padded
// (r10's lowest-conflict layout). LDS 50.4 KB -> 2 blocks fit.
// THE EXPERIMENT: __launch_bounds__(512, 4). Unlike rounds 4/9 (cap 128 vs
// working set ~150 -> spill storm), the footprint has converged to ~128
// total (r11: 88 VGPR + ~40 AGPR), so the cap now costs ~0 spills and buys
// 16 waves/CU — the first clean test of the latency-bound diagnosis.
__global__ __launch_bounds__(512, 4) void attn_kernel(
        const float* __restrict__ Kg, const float* __restrict__ Vg,
        const int* __restrict__ maskg, const float* __restrict__ qenc,
        float* __restrict__ part) {
    int blk = blockIdx.x;
    int c = blk & (CT - 1);
    int b = blk / CT;
    int tid = threadIdx.x;
    int wid = tid >> 6;
    int lane = tid & 63;
    int h = wid & 3;               // head
    int qhalf = wid >> 2;          // 0: q 0..15, 1: q 16..31
    int g = lane >> 4;             // lane group 0..3
    int q15 = lane & 15;

    __shared__ __align__(16) __bf16 Kf[2][2][2][4][65][8];   // 33,280 B (dbuf)
    __shared__ __align__(16) __bf16 Vf[2][8][64][8];         // 16,384 B (single)
    __shared__ float Vt_s[2][32];                            // V cols 128,129
    __shared__ int   msks[32];

    // stage geometry (key permutation for shfl_xor(32) P-exchange)
    int skey = tid >> 4;           // physical key 0..31
    int sdhi = tid & 15;           // d-chunk: d0 = sdhi*8
    int sa = skey >> 3, sb = skey & 7;
    int skh = sb >> 2;                               // target mfma instance
    int sm  = skh ? 4 * (sa ^ 2) + (sb & 3)          // target mfma row
                  : 4 * sa + sb;
    int slK = sm + 16 * (sdhi & 3);
    int skst = sdhi >> 2;
    int sv = tid & 127, skb = tid >> 7;              // skb 0..3
    int svc = sv >> 4, slV = (sv & 15) + 16 * skb;

    const float* Kb = Kg + (size_t)b * NN * KD;
    const float* Vb = Vg + (size_t)b * NN * VD;
    const int*   Mb = maskg + b * NN;

    float4 kfa, kfb;
    float  vf[8];
    float2 vt = {0.f, 0.f};
    int    mk = 0;

    auto sloadK = [&](int T) {
        int n0 = c * NCH + T * 32;
        const float* ks = Kb + (size_t)(n0 + skey) * KD + sdhi * 8;
        kfa = *(const float4*)ks;
        kfb = *(const float4*)(ks + 4);
    };
    auto sloadV = [&](int T) {
        int n0 = c * NCH + T * 32;
        const float* vs = Vb + (size_t)(n0 + skb * 8) * VD + sv;
        #pragma unroll
        for (int j = 0; j < 8; ++j) vf[j] = vs[(size_t)j * VD];
        if (tid < 32) {
            vt = *(const float2*)(Vb + (size_t)(n0 + tid) * VD + 128);
            mk = Mb[n0 + tid];
        }
    };
    auto swriteK = [&](int buf) {
        bf16x8 hh, ll;
        split8(kfa, kfb, &hh, &ll);
        *(bf16x8*)&Kf[buf][0][skh][skst][slK][0] = hh;
        *(bf16x8*)&Kf[buf][1][skh][skst][slK][0] = ll;
    };
    auto swriteV = [&]() {
        bf16x8 hh, ll;
        float4 va = {vf[0], vf[1], vf[2], vf[3]};
        float4 vb2 = {vf[4], vf[5], vf[6], vf[7]};
        split8(va, vb2, &hh, &ll);
        *(bf16x8*)&Vf[0][svc][slV][0] = hh;
        *(bf16x8*)&Vf[1][svc][slV][0] = ll;
        if (tid < 32) {
            Vt_s[0][tid] = vt.x;
            Vt_s[1][tid] = vt.y;
            msks[tid] = mk;
        }
    };

    sloadK(0);
    sloadV(0);

    // ---- Q B-frags (hi/lo): lane holds Q[d=kst*32+g*8+j][q=qhalf*16+q15]
    //      (overlaps tile-0 load flight)
    bf16x8 qh[4], ql[4];
    {
        const float* qrow = qenc + (size_t)(b * JJ + qhalf * 16 + q15) * 512
                            + h * KD + g * 8;
        #pragma unroll
        for (int kst = 0; kst < 4; ++kst) {
            float4 qa = *(const float4*)(qrow + kst * 32);
            float4 qb = *(const float4*)(qrow + kst * 32 + 4);
            split8(qa, qb, &qh[kst], &ql[kst]);
        }
    }

    swriteK(0);                    // waits K(0); publishes Kf[0]
    sloadK(1);                     // kf regs free again
    __builtin_amdgcn_sched_barrier(0);

    f32x4 O[8];
    #pragma unroll
    for (int vc = 0; vc < 8; ++vc)
        #pragma unroll
        for (int r = 0; r < 4; ++r) O[vc][r] = 0.f;
    float acct0 = 0.f, acct1 = 0.f;
    float m_run = -1e30f, l_run = 0.f;

    __syncthreads();               // one-time full sync: Kf[0] visible

    for (int t = 0; t < TIL; ++t) {
        int cur = t & 1;

        // ---- A/B: publish V(t) and K(t+1) (regs loaded last iter)
        swriteV();
        if (t + 1 < TIL) swriteK(cur ^ 1);
        __builtin_amdgcn_sched_barrier(0);

        // ---- D: S = mfma(K, Q): C[m][q], 2 instances (kh) x 12 MFMA
        f32x4 S[2];
        #pragma unroll
        for (int kh = 0; kh < 2; ++kh)
            #pragma unroll
            for (int r = 0; r < 4; ++r) S[kh][r] = 0.f;
        #pragma unroll
        for (int kst = 0; kst < 4; ++kst) {
            #pragma unroll
            for (int kh = 0; kh < 2; ++kh) {
                bf16x8 khf = *(const bf16x8*)&Kf[cur][0][kh][kst][lane][0];
                bf16x8 klf = *(const bf16x8*)&Kf[cur][1][kh][kst][lane][0];
                S[kh] = __builtin_amdgcn_mfma_f32_16x16x32_bf16(khf, qh[kst], S[kh], 0, 0, 0);
                S[kh] = __builtin_amdgcn_mfma_f32_16x16x32_bf16(khf, ql[kst], S[kh], 0, 0, 0);
                S[kh] = __builtin_amdgcn_mfma_f32_16x16x32_bf16(klf, qh[kst], S[kh], 0, 0, 0);
            }
        }

        barrier_novm();            // bar1: V(t)/mask visible

        // ---- C: prefetch next tiles (fly under softmax+PV; consumed at
        //         next-tile swrites via compiler-counted vmcnt)
        if (t + 2 < TIL) sloadK(t + 2);
        if (t + 1 < TIL) sloadV(t + 1);
        __builtin_amdgcn_sched_barrier(0);

        // ---- E: mask + scale + defer-max online softmax
        unsigned int mword = (unsigned int)__ballot(msks[lane & 31] != 0);
        const float sc = 0.08838834764831845f;
        float sp[8];
        float rm = -1e30f;
        #pragma unroll
        for (int r = 0; r < 4; ++r) {
            int key0 = 8 * g + r;
            float s0 = ((mword >> key0) & 1u) ? -1e30f : S[0][r] * sc;
            sp[r] = s0;
            rm = fmaxf(rm, s0);
            int key1 = 8 * (g ^ 2) + 4 + r;
            float s1 = ((mword >> key1) & 1u) ? -1e30f : S[1][r] * sc;
            sp[4 + r] = s1;
            rm = fmaxf(rm, s1);
        }
        rm = fmaxf(rm, __shfl_xor(rm, 16));
        rm = fmaxf(rm, __shfl_xor(rm, 32));
        if (!__all(rm <= m_run + 8.f)) {          // T13 defer-max
            float mn = fmaxf(m_run, rm);
            float rs = __expf(m_run - mn);
            m_run = mn;
            l_run *= rs; acct0 *= rs; acct1 *= rs;
            #pragma unroll
            for (int r = 0; r < 4; ++r) {
                float rr = __shfl(rs, g * 4 + r);  // rare path
                #pragma unroll
                for (int vc = 0; vc < 8; ++vc) O[vc][r] *= rr;
            }
        }
        float ps = 0.f;
        #pragma unroll
        for (int i = 0; i < 8; ++i) {
            float p = __expf(sp[i] - m_run);       // bounded by e^8
            sp[i] = p;
            ps += p;
        }
        ps += __shfl_xor(ps, 16);
        ps += __shfl_xor(ps, 32);
        l_run += ps;

        // ---- fp32 tail: out[q][128|129]
        #pragma unroll
        for (int r = 0; r < 4; ++r) {
            int key0 = 8 * g + r;
            int key1 = 8 * (g ^ 2) + 4 + r;
            acct0 += sp[r] * Vt_s[0][key0] + sp[4 + r] * Vt_s[0][key1];
            acct1 += sp[r] * Vt_s[1][key0] + sp[4 + r] * Vt_s[1][key1];
        }

        // ---- P -> PV A-frag: own kh0 words + xor-32 swapped kh1 words
        unsigned w0h = packhi(sp[0], sp[1]), w1h = packhi(sp[2], sp[3]);
        unsigned w2h = packhi(sp[4], sp[5]), w3h = packhi(sp[6], sp[7]);
        unsigned w0l = packhi(sp[0] - truncbf(sp[0]), sp[1] - truncbf(sp[1]));
        unsigned w1l = packhi(sp[2] - truncbf(sp[2]), sp[3] - truncbf(sp[3]));
        unsigned w2l = packhi(sp[4] - truncbf(sp[4]), sp[5] - truncbf(sp[5]));
        unsigned w3l = packhi(sp[6] - truncbf(sp[6]), sp[7] - truncbf(sp[7]));
        FW4 PH, PL;
        PH.u[0] = w0h; PH.u[1] = w1h;
        PH.u[2] = __shfl_xor(w2h, 32);
        PH.u[3] = __shfl_xor(w3h, 32);
        PL.u[0] = w0l; PL.u[1] = w1l;
        PL.u[2] = __shfl_xor(w2l, 32);
        PL.u[3] = __shfl_xor(w3l, 32);
        bf16x8 PAH = PH.v, PAL = PL.v;

        // ---- F: O += P . V (3-term, 8 independent chains)
        #pragma unroll
        for (int vc = 0; vc < 8; ++vc) {
            bf16x8 vh = *(const bf16x8*)&Vf[0][vc][lane][0];
            bf16x8 vl = *(const bf16x8*)&Vf[1][vc][lane][0];
            O[vc] = __builtin_amdgcn_mfma_f32_16x16x32_bf16(PAH, vh, O[vc], 0, 0, 0);
            O[vc] = __builtin_amdgcn_mfma_f32_16x16x32_bf16(PAL, vh, O[vc], 0, 0, 0);
            O[vc] = __builtin_amdgcn_mfma_f32_16x16x32_bf16(PAH, vl, O[vc], 0, 0, 0);
        }

        barrier_novm();            // bar2: frees Vf/Kf[cur]; loads stay aloft
    }

    // ---- write partials (PV C layout: q = g*4+r, v = vc*16+q15)
    float* P = part + (size_t)((b * HH + h) * CT + c) * PSTRIDE;
    if (lane < 16) {
        P[qhalf * 16 + lane] = m_run;
        P[JJ + qhalf * 16 + lane] = l_run;
    }
    float* A = P + 2 * JJ;
    #pragma unroll
    for (int vc = 0; vc < 8; ++vc) {
        #pragma unroll
        for (int r = 0; r < 4; ++r) {
            int q = qhalf * 16 + g * 4 + r;
            A[q * VD + vc * 16 + q15] = O[vc][r];
        }
    }
    acct0 += __shfl_xor(acct0, 16);
    acct0 += __shfl_xor(acct0, 32);
    acct1 += __shfl_xor(acct1, 16);
    acct1 += __shfl_xor(acct1, 32);
    if (lane < 16) {
        A[(qhalf * 16 + lane) * VD + 128] = acct0;
        A[(qhalf * 16 + lane) * VD + 129] = acct1;
    }
}

// -------------------------------------------- fused combine + output MLP ----
__global__ __launch_bounds__(64) void comb_mlp_kernel(
        const float* __restrict__ part,
        const float* __restrict__ W3, const float* __restrict__ b3,
        const float* __restrict__ W4, const float* __restrict__ b4,
        const float* __restrict__ W5, const float* __restrict__ b5,
        float* __restrict__ out) {
    int row = blockIdx.x;          // b*J + j
    int b = row >> 5;
    int j = row & 31;
    int t = threadIdx.x;
    __shared__ float w_s[HH][CT];
    __shared__ float x[HH * VD];
    __shared__ float h1[64];
    __shared__ float h2[32];

    if (t < HH * CT) {
        int h = t / CT, cc = t % CT;
        const float* P = part + (size_t)((b * HH + h) * CT + cc) * PSTRIDE;
        float m = P[j];
        float l = P[JJ + j];
        float mm = m;
        #pragma unroll
        for (int s = 1; s < CT; s <<= 1) mm = fmaxf(mm, __shfl_xor(mm, s));
        float e = __expf(m - mm);
        float L = l * e;
        #pragma unroll
        for (int s = 1; s < CT; s <<= 1) L += __shfl_xor(L, s);
        w_s[h][cc] = (L > 0.f) ? e / L : 0.f;
    }
    __syncthreads();

    for (int idx = t; idx < HH * VD; idx += 64) {
        int h = idx / VD, v = idx - h * VD;
        const float* A = part + (size_t)(b * HH + h) * CT * PSTRIDE + 2 * JJ + j * VD + v;
        float o = 0.f;
        #pragma unroll 4
        for (int cc = 0; cc < CT; ++cc) o += w_s[h][cc] * A[(size_t)cc * PSTRIDE];
        x[idx] = o;
    }
    __syncthreads();

    float a0 = 0.f, a1 = 0.f, a2 = 0.f, a3 = 0.f;
    for (int i = 0; i < HH * VD; i += 4) {
        a0 += x[i] * W3[i * 64 + t];
        a1 += x[i + 1] * W3[(i + 1) * 64 + t];
        a2 += x[i + 2] * W3[(i + 2) * 64 + t];
        a3 += x[i + 3] * W3[(i + 3) * 64 + t];
    }
    h1[t] = fmaxf(b3[t] + (a0 + a1) + (a2 + a3), 0.f);
    __syncthreads();
    if (t < 32) {
        float c0 = 0.f, c1 = 0.f;
        for (int i = 0; i < 64; i += 2) {
            c0 += h1[i] * W4[i * 32 + t];
            c1 += h1[i + 1] * W4[(i + 1) * 32 + t];
        }
        h2[t] = fmaxf(b4[t] + c0 + c1, 0.f);
    }
    __syncthreads();
    if (t == 0) {
        float a3f = b5[0];
        for (int i = 0; i < 32; ++i) a3f += h2[i] * W5[i];
        out[row] = a3f;
    }
}

extern "C" void kernel_launch(void* const* d_in, const int* in_sizes, int n_in,
                              void* d_out, int out_size, void* d_ws, size_t ws_size,
                              hipStream_t stream) {
    const float* jq = (const float*)d_in[0];
    const float* Kg = (const float*)d_in[1];
    const float* Vg = (const float*)d_in[2];
    const int* mask = (const int*)d_in[3];
    const float* W1 = (const float*)d_in[4];
    const float* b1 = (const float*)d_in[5];
    const float* W2 = (const float*)d_in[6];
    const float* b2 = (const float*)d_in[7];
    const float* W3 = (const float*)d_in[8];
    const float* b3 = (const float*)d_in[9];
    const float* W4 = (const float*)d_in[10];
    const float* b4 = (const float*)d_in[11];
    const float* W5 = (const float*)d_in[12];
    const float* b5 = (const float*)d_in[13];
    float* out = (float*)d_out;

    float* ws = (float*)d_ws;
    float* qenc = ws;                                   // B*J*512 floats
    float* part = qenc + (size_t)BB * JJ * HH * KD;     // B*H*CT*PSTRIDE floats

    enc_kernel<<<BB * JJ, 64, 0, stream>>>(jq, W1, b1, W2, b2, qenc);
    attn_kernel<<<BB * CT, 512, 0, stream>>>(Kg, Vg, mask, qenc, part);
    comb_mlp_kernel<<<BB * JJ, 64, 0, stream>>>(part, W3, b3, W4, b4, W5, b5, out);
}

// Round 16
// 117.006 us; speedup vs baseline: 1.7415x; 1.7415x over previous
//
#include <hip/hip_runtime.h>
#include <hip/hip_bf16.h>

#define BB 64
#define JJ 32
#define NN 4096
#define QD 130
#define KD 128
#define VD 130
#define HH 4
#define CT 4
#define TN 64
#define NCH (NN / CT)                 // 1024
#define TIL (NCH / TN)                // 16
#define PSTRIDE (JJ + JJ + JJ * VD)   // 4224 floats per partial block

typedef __attribute__((ext_vector_type(8))) __bf16 bf16x8;
typedef __attribute__((ext_vector_type(4))) float  f32x4;

union FW4 { unsigned int u[4]; bf16x8 v; };

#define SEL_HI 0x07060302u

__device__ __forceinline__ unsigned int packhi(float f0, float f1) {
    return __builtin_amdgcn_perm(__float_as_uint(f1), __float_as_uint(f0), SEL_HI);
}
__device__ __forceinline__ float truncbf(float f) {
    return __uint_as_float(__float_as_uint(f) & 0xFFFF0000u);
}
// truncation split: 8 floats -> hi/lo bf16x8 planes (f = h + l + O(2^-17))
__device__ __forceinline__ void split8(float4 a, float4 b, bf16x8* h, bf16x8* l) {
    FW4 H, L;
    H.u[0] = packhi(a.x, a.y);
    H.u[1] = packhi(a.z, a.w);
    H.u[2] = packhi(b.x, b.y);
    H.u[3] = packhi(b.z, b.w);
    L.u[0] = packhi(a.x - truncbf(a.x), a.y - truncbf(a.y));
    L.u[1] = packhi(a.z - truncbf(a.z), a.w - truncbf(a.w));
    L.u[2] = packhi(b.x - truncbf(b.x), b.y - truncbf(b.y));
    L.u[3] = packhi(b.z - truncbf(b.z), b.w - truncbf(b.w));
    *h = H.v; *l = L.v;
}

// LDS-visibility-only barrier — does NOT drain vmcnt; in-flight global
// register loads survive (compiler inserts counted vmcnt at their consumer).
__device__ __forceinline__ void barrier_novm() {
    __builtin_amdgcn_sched_barrier(0);
    asm volatile("s_waitcnt lgkmcnt(0)" ::: "memory");
    __builtin_amdgcn_s_barrier();
    __builtin_amdgcn_sched_barrier(0);
}

// ---------------------------------------------------------------- encoder ---
__global__ __launch_bounds__(64) void enc_kernel(
        const float* __restrict__ jq,
        const float* __restrict__ W1, const float* __restrict__ b1,
        const float* __restrict__ W2, const float* __restrict__ b2,
        float* __restrict__ qenc) {
    int row = blockIdx.x;          // b*J + j
    int t = threadIdx.x;           // 0..63
    __shared__ float x[QD];
    __shared__ float h[64];
    for (int i = t; i < QD; i += 64) x[i] = jq[row * QD + i];
    __syncthreads();
    float a0 = 0.f, a1 = 0.f;
    for (int i = 0; i < QD - 1; i += 2) {
        a0 += x[i] * W1[i * 64 + t];
        a1 += x[i + 1] * W1[(i + 1) * 64 + t];
    }
    h[t] = fmaxf(b1[t] + a0 + a1, 0.f);
    __syncthreads();
    float a[8];
    #pragma unroll
    for (int s = 0; s < 8; ++s) a[s] = b2[t + 64 * s];
    for (int i = 0; i < 64; ++i) {
        float hv = h[i];
        #pragma unroll
        for (int s = 0; s < 8; ++s) a[s] += hv * W2[i * 512 + t + 64 * s];
    }
    #pragma unroll
    for (int s = 0; s < 8; ++s) qenc[row * 512 + t + 64 * s] = a[s];
}

// -------------------------------------------------------------- attention ---
// Block = (b, chunk of 1024 keys), 512 threads = 8 waves = 4 heads x 2
// q-halves, TN=64 keys per tile (vs 32): HALVES the per-key cost of the
// phase machinery (2 barriers, 64-bit ballot, shfl-reduction chains,
// defer-max check per 64 keys instead of per 32) while per-key MFMA/LDS/
// staging work is unchanged. 16x16x32 MFMA; key-permuted K layout so the
// P->A-frag exchange is 4 shfl_xor(32) per 32-key half. K double-buffered,
// V single-buffered (2-barrier schedule). LDS ~100 KB, 1 block/CU.
// (512,2): NEVER force more waves/EU — rounds 4, 9, 15 all proved a cap
// below VGPR+AGPR working set (~160) triggers a spill storm (r15: cap 128
// -> 64 VGPR + 265 MB extra traffic at 43% occupancy, 1.7x SLOWER).
__global__ __launch_bounds__(512, 2) void attn_kernel(
        const float* __restrict__ Kg, const float* __restrict__ Vg,
        const int* __restrict__ maskg, const float* __restrict__ qenc,
        float* __restrict__ part) {
    int blk = blockIdx.x;
    int c = blk & (CT - 1);
    int b = blk >> 2;              // CT==4
    int tid = threadIdx.x;
    int wid = tid >> 6;
    int lane = tid & 63;
    int h = wid & 3;               // head
    int qhalf = wid >> 2;          // 0: q 0..15, 1: q 16..31
    int g = lane >> 4;             // lane group 0..3
    int q15 = lane & 15;

    // K frags: [dbuf][plane][kh 0..3][kst 0..3][slot 65][8]  (66,560 B)
    __shared__ __align__(16) __bf16 Kf[2][2][4][4][65][8];
    // V frags: [plane][ks2 0..1][vc 0..7][slot 64][8]        (32,768 B)
    __shared__ __align__(16) __bf16 Vf[2][2][8][64][8];
    __shared__ float Vt_s[2][TN];                            // V cols 128,129
    __shared__ int   msks[TN];

    // stage geometry. K: 1024 slots = key(64) x dchunk(16); thread p0=tid
    // handles (skey, sdhi) in keys 0..31, p1=tid+512 the same at key+32.
    int skey = tid >> 4;           // 0..31
    int sdhi = tid & 15;           // d0 = sdhi*8
    int sa = skey >> 3, sb = skey & 7;
    int ssub = sb >> 2;                              // mfma sub-instance
    int sm  = ssub ? 4 * (sa ^ 2) + (sb & 3)         // key-permuted row
                   : 4 * sa + sb;
    int slK = sm + 16 * (sdhi & 3);
    int skst = sdhi >> 2;
    // V: 1024 slots = col(128) x rowgrp(8); p0 -> ks2=0 rows skb*8.., p1 ->
    // ks2=1 rows 32+skb*8.. (same col, same lane-slot).
    int sv = tid & 127, skb = tid >> 7;              // skb 0..3
    int svc = sv >> 4, slV = (sv & 15) + 16 * skb;

    const float* Kb = Kg + (size_t)b * NN * KD;
    const float* Vb = Vg + (size_t)b * NN * VD;
    const int*   Mb = maskg + b * NN;

    float4 kfa0, kfb0, kfa1, kfb1;
    float  vf0[8], vf1[8];
    float2 vt = {0.f, 0.f};
    int    mk = 0;

    auto sloadK = [&](int T) {
        int n0 = c * NCH + T * TN;
        const float* ks0 = Kb + (size_t)(n0 + skey) * KD + sdhi * 8;
        kfa0 = *(const float4*)ks0;
        kfb0 = *(const float4*)(ks0 + 4);
        const float* ks1 = Kb + (size_t)(n0 + 32 + skey) * KD + sdhi * 8;
        kfa1 = *(const float4*)ks1;
        kfb1 = *(const float4*)(ks1 + 4);
    };
    auto sloadV = [&](int T) {
        int n0 = c * NCH + T * TN;
        const float* vs0 = Vb + (size_t)(n0 + skb * 8) * VD + sv;
        #pragma unroll
        for (int j = 0; j < 8; ++j) vf0[j] = vs0[(size_t)j * VD];
        const float* vs1 = Vb + (size_t)(n0 + 32 + skb * 8) * VD + sv;
        #pragma unroll
        for (int j = 0; j < 8; ++j) vf1[j] = vs1[(size_t)j * VD];
        if (tid < TN) {
            vt = *(const float2*)(Vb + (size_t)(n0 + tid) * VD + 128);
            mk = Mb[n0 + tid];
        }
    };
    auto swriteK = [&](int buf) {
        bf16x8 hh, ll;
        split8(kfa0, kfb0, &hh, &ll);
        *(bf16x8*)&Kf[buf][0][ssub][skst][slK][0] = hh;
        *(bf16x8*)&Kf[buf][1][ssub][skst][slK][0] = ll;
        split8(kfa1, kfb1, &hh, &ll);
        *(bf16x8*)&Kf[buf][0][2 + ssub][skst][slK][0] = hh;
        *(bf16x8*)&Kf[buf][1][2 + ssub][skst][slK][0] = ll;
    };
    auto swriteV = [&]() {
        bf16x8 hh, ll;
        float4 va = {vf0[0], vf0[1], vf0[2], vf0[3]};
        float4 vb2 = {vf0[4], vf0[5], vf0[6], vf0[7]};
        split8(va, vb2, &hh, &ll);
        *(bf16x8*)&Vf[0][0][svc][slV][0] = hh;
        *(bf16x8*)&Vf[1][0][svc][slV][0] = ll;
        float4 vc3 = {vf1[0], vf1[1], vf1[2], vf1[3]};
        float4 vd = {vf1[4], vf1[5], vf1[6], vf1[7]};
        split8(vc3, vd, &hh, &ll);
        *(bf16x8*)&Vf[0][1][svc][slV][0] = hh;
        *(bf16x8*)&Vf[1][1][svc][slV][0] = ll;
        if (tid < TN) {
            Vt_s[0][tid] = vt.x;
            Vt_s[1][tid] = vt.y;
            msks[tid] = mk;
        }
    };

    sloadK(0);
    sloadV(0);

    // ---- Q B-frags (hi/lo): lane holds Q[d=kst*32+g*8+j][q=qhalf*16+q15]
    bf16x8 qh[4], ql[4];
    {
        const float* qrow = qenc + (size_t)(b * JJ + qhalf * 16 + q15) * 512
                            + h * KD + g * 8;
        #pragma unroll
        for (int kst = 0; kst < 4; ++kst) {
            float4 qa = *(const float4*)(qrow + kst * 32);
            float4 qb = *(const float4*)(qrow + kst * 32 + 4);
            split8(qa, qb, &qh[kst], &ql[kst]);
        }
    }

    swriteK(0);                    // publishes Kf[0]
    sloadK(1);                     // K(1) regs in flight
    __builtin_amdgcn_sched_barrier(0);

    f32x4 O[8];
    #pragma unroll
    for (int vc = 0; vc < 8; ++vc)
        #pragma unroll
        for (int r = 0; r < 4; ++r) O[vc][r] = 0.f;
    float acct0 = 0.f, acct1 = 0.f;
    float m_run = -1e30f, l_run = 0.f;

    __syncthreads();               // one-time full sync: Kf[0] visible

    for (int t = 0; t < TIL; ++t) {
        int cur = t & 1;

        // ---- A/B: publish V(t) and K(t+1) (regs loaded last iter)
        swriteV();
        if (t + 1 < TIL) swriteK(cur ^ 1);
        __builtin_amdgcn_sched_barrier(0);

        // ---- D: S = mfma(K, Q): 4 instances (kh) x 12 MFMA = 64 keys
        f32x4 S[4];
        #pragma unroll
        for (int kh = 0; kh < 4; ++kh)
            #pragma unroll
            for (int r = 0; r < 4; ++r) S[kh][r] = 0.f;
        #pragma unroll
        for (int kst = 0; kst < 4; ++kst) {
            #pragma unroll
            for (int kh = 0; kh < 4; ++kh) {
                bf16x8 khf = *(const bf16x8*)&Kf[cur][0][kh][kst][lane][0];
                bf16x8 klf = *(const bf16x8*)&Kf[cur][1][kh][kst][lane][0];
                S[kh] = __builtin_amdgcn_mfma_f32_16x16x32_bf16(khf, qh[kst], S[kh], 0, 0, 0);
                S[kh] = __builtin_amdgcn_mfma_f32_16x16x32_bf16(khf, ql[kst], S[kh], 0, 0, 0);
                S[kh] = __builtin_amdgcn_mfma_f32_16x16x32_bf16(klf, qh[kst], S[kh], 0, 0, 0);
            }
        }

        barrier_novm();            // bar1: V(t)/mask visible

        // ---- C: prefetch next tiles (fly under softmax+PV; consumed by
        //         next-iter swrites via compiler-counted vmcnt)
        if (t + 2 < TIL) sloadK(t + 2);
        if (t + 1 < TIL) sloadV(t + 1);
        __builtin_amdgcn_sched_barrier(0);

        // ---- E: mask + scale + defer-max online softmax over 64 keys
        unsigned long long mword = __ballot(msks[lane] != 0);
        const float sc = 0.08838834764831845f;
        float sp[16];
        float rm = -1e30f;
        #pragma unroll
        for (int r = 0; r < 4; ++r) {
            int key0 = 8 * g + r;
            int key1 = 8 * (g ^ 2) + 4 + r;
            float s0 = ((mword >> key0) & 1ull) ? -1e30f : S[0][r] * sc;
            float s1 = ((mword >> key1) & 1ull) ? -1e30f : S[1][r] * sc;
            float s2 = ((mword >> (32 + key0)) & 1ull) ? -1e30f : S[2][r] * sc;
            float s3 = ((mword >> (32 + key1)) & 1ull) ? -1e30f : S[3][r] * sc;
            sp[r] = s0; sp[4 + r] = s1; sp[8 + r] = s2; sp[12 + r] = s3;
            rm = fmaxf(rm, fmaxf(fmaxf(s0, s1), fmaxf(s2, s3)));
        }
        rm = fmaxf(rm, __shfl_xor(rm, 16));
        rm = fmaxf(rm, __shfl_xor(rm, 32));
        if (!__all(rm <= m_run + 8.f)) {          // T13 defer-max
            float mn = fmaxf(m_run, rm);
            float rs = __expf(m_run - mn);
            m_run = mn;
            l_run *= rs; acct0 *= rs; acct1 *= rs;
            #pragma unroll
            for (int r = 0; r < 4; ++r) {
                float rr = __shfl(rs, g * 4 + r);  // rare path
                #pragma unroll
                for (int vc = 0; vc < 8; ++vc) O[vc][r] *= rr;
            }
        }
        float ps = 0.f;
        #pragma unroll
        for (int i = 0; i < 16; ++i) {
            float p = __expf(sp[i] - m_run);       // bounded by e^8
            sp[i] = p;
            ps += p;
        }
        ps += __shfl_xor(ps, 16);
        ps += __shfl_xor(ps, 32);
        l_run += ps;

        // ---- fp32 tail: out[q][128|129] over 64 keys
        #pragma unroll
        for (int r = 0; r < 4; ++r) {
            int key0 = 8 * g + r;
            int key1 = 8 * (g ^ 2) + 4 + r;
            acct0 += sp[r] * Vt_s[0][key0] + sp[4 + r] * Vt_s[0][key1]
                   + sp[8 + r] * Vt_s[0][32 + key0] + sp[12 + r] * Vt_s[0][32 + key1];
            acct1 += sp[r] * Vt_s[1][key0] + sp[4 + r] * Vt_s[1][key1]
                   + sp[8 + r] * Vt_s[1][32 + key0] + sp[12 + r] * Vt_s[1][32 + key1];
        }

        // ---- P -> PV A-frags, one per 32-key half (4 shfl_xor(32) each)
        bf16x8 PAH0, PAL0, PAH1, PAL1;
        {
            unsigned w0h = packhi(sp[0], sp[1]), w1h = packhi(sp[2], sp[3]);
            unsigned w2h = packhi(sp[4], sp[5]), w3h = packhi(sp[6], sp[7]);
            unsigned w0l = packhi(sp[0] - truncbf(sp[0]), sp[1] - truncbf(sp[1]));
            unsigned w1l = packhi(sp[2] - truncbf(sp[2]), sp[3] - truncbf(sp[3]));
            unsigned w2l = packhi(sp[4] - truncbf(sp[4]), sp[5] - truncbf(sp[5]));
            unsigned w3l = packhi(sp[6] - truncbf(sp[6]), sp[7] - truncbf(sp[7]));
            FW4 PH, PL;
            PH.u[0] = w0h; PH.u[1] = w1h;
            PH.u[2] = __shfl_xor(w2h, 32);
            PH.u[3] = __shfl_xor(w3h, 32);
            PL.u[0] = w0l; PL.u[1] = w1l;
            PL.u[2] = __shfl_xor(w2l, 32);
            PL.u[3] = __shfl_xor(w3l, 32);
            PAH0 = PH.v; PAL0 = PL.v;
        }
        {
            unsigned w0h = packhi(sp[8], sp[9]), w1h = packhi(sp[10], sp[11]);
            unsigned w2h = packhi(sp[12], sp[13]), w3h = packhi(sp[14], sp[15]);
            unsigned w0l = packhi(sp[8] - truncbf(sp[8]), sp[9] - truncbf(sp[9]));
            unsigned w1l = packhi(sp[10] - truncbf(sp[10]), sp[11] - truncbf(sp[11]));
            unsigned w2l = packhi(sp[12] - truncbf(sp[12]), sp[13] - truncbf(sp[13]));
            unsigned w3l = packhi(sp[14] - truncbf(sp[14]), sp[15] - truncbf(sp[15]));
            FW4 PH, PL;
            PH.u[0] = w0h; PH.u[1] = w1h;
            PH.u[2] = __shfl_xor(w2h, 32);
            PH.u[3] = __shfl_xor(w3h, 32);
            PL.u[0] = w0l; PL.u[1] = w1l;
            PL.u[2] = __shfl_xor(w2l, 32);
            PL.u[3] = __shfl_xor(w3l, 32);
            PAH1 = PH.v; PAL1 = PL.v;
        }

        // ---- F: O += P . V (3-term, 2 k-halves, 8 independent chains)
        #pragma unroll
        for (int vc = 0; vc < 8; ++vc) {
            bf16x8 vh0 = *(const bf16x8*)&Vf[0][0][vc][lane][0];
            bf16x8 vl0 = *(const bf16x8*)&Vf[1][0][vc][lane][0];
            O[vc] = __builtin_amdgcn_mfma_f32_16x16x32_bf16(PAH0, vh0, O[vc], 0, 0, 0);
            O[vc] = __builtin_amdgcn_mfma_f32_16x16x32_bf16(PAL0, vh0, O[vc], 0, 0, 0);
            O[vc] = __builtin_amdgcn_mfma_f32_16x16x32_bf16(PAH0, vl0, O[vc], 0, 0, 0);
            bf16x8 vh1 = *(const bf16x8*)&Vf[0][1][vc][lane][0];
            bf16x8 vl1 = *(const bf16x8*)&Vf[1][1][vc][lane][0];
            O[vc] = __builtin_amdgcn_mfma_f32_16x16x32_bf16(PAH1, vh1, O[vc], 0, 0, 0);
            O[vc] = __builtin_amdgcn_mfma_f32_16x16x32_bf16(PAL1, vh1, O[vc], 0, 0, 0);
            O[vc] = __builtin_amdgcn_mfma_f32_16x16x32_bf16(PAH1, vl1, O[vc], 0, 0, 0);
        }

        barrier_novm();            // bar2: frees Vf/Kf[cur]; loads stay aloft
    }

    // ---- write partials (PV C layout: q = g*4+r, v = vc*16+q15)
    float* P = part + (size_t)((b * HH + h) * CT + c) * PSTRIDE;
    if (lane < 16) {
        P[qhalf * 16 + lane] = m_run;
        P[JJ + qhalf * 16 + lane] = l_run;
    }
    float* A = P + 2 * JJ;
    #pragma unroll
    for (int vc = 0; vc < 8; ++vc) {
        #pragma unroll
        for (int r = 0; r < 4; ++r) {
            int q = qhalf * 16 + g * 4 + r;
            A[q * VD + vc * 16 + q15] = O[vc][r];
        }
    }
    acct0 += __shfl_xor(acct0, 16);
    acct0 += __shfl_xor(acct0, 32);
    acct1 += __shfl_xor(acct1, 16);
    acct1 += __shfl_xor(acct1, 32);
    if (lane < 16) {
        A[(qhalf * 16 + lane) * VD + 128] = acct0;
        A[(qhalf * 16 + lane) * VD + 129] = acct1;
    }
}

// -------------------------------------------- fused combine + output MLP ----
__global__ __launch_bounds__(64) void comb_mlp_kernel(
        const float* __restrict__ part,
        const float* __restrict__ W3, const float* __restrict__ b3,
        const float* __restrict__ W4, const float* __restrict__ b4,
        const float* __restrict__ W5, const float* __restrict__ b5,
        float* __restrict__ out) {
    int row = blockIdx.x;          // b*J + j
    int b = row >> 5;
    int j = row & 31;
    int t = threadIdx.x;
    __shared__ float w_s[HH][CT];
    __shared__ float x[HH * VD];
    __shared__ float h1[64];
    __shared__ float h2[32];

    if (t < HH * CT) {             // 16 threads
        int h = t / CT, cc = t % CT;
        const float* P = part + (size_t)((b * HH + h) * CT + cc) * PSTRIDE;
        float m = P[j];
        float l = P[JJ + j];
        float mm = m;
        #pragma unroll
        for (int s = 1; s < CT; s <<= 1) mm = fmaxf(mm, __shfl_xor(mm, s));
        float e = __expf(m - mm);
        float L = l * e;
        #pragma unroll
        for (int s = 1; s < CT; s <<= 1) L += __shfl_xor(L, s);
        w_s[h][cc] = (L > 0.f) ? e / L : 0.f;
    }
    __syncthreads();

    for (int idx = t; idx < HH * VD; idx += 64) {
        int h = idx / VD, v = idx - h * VD;
        const float* A = part + (size_t)(b * HH + h) * CT * PSTRIDE + 2 * JJ + j * VD + v;
        float o = 0.f;
        #pragma unroll
        for (int cc = 0; cc < CT; ++cc) o += w_s[h][cc] * A[(size_t)cc * PSTRIDE];
        x[idx] = o;
    }
    __syncthreads();

    float a0 = 0.f, a1 = 0.f, a2 = 0.f, a3 = 0.f;
    for (int i = 0; i < HH * VD; i += 4) {
        a0 += x[i] * W3[i * 64 + t];
        a1 += x[i + 1] * W3[(i + 1) * 64 + t];
        a2 += x[i + 2] * W3[(i + 2) * 64 + t];
        a3 += x[i + 3] * W3[(i + 3) * 64 + t];
    }
    h1[t] = fmaxf(b3[t] + (a0 + a1) + (a2 + a3), 0.f);
    __syncthreads();
    if (t < 32) {
        float c0 = 0.f, c1 = 0.f;
        for (int i = 0; i < 64; i += 2) {
            c0 += h1[i] * W4[i * 32 + t];
            c1 += h1[i + 1] * W4[(i + 1) * 32 + t];
        }
        h2[t] = fmaxf(b4[t] + c0 + c1, 0.f);
    }
    __syncthreads();
    if (t == 0) {
        float a3f = b5[0];
        for (int i = 0; i < 32; ++i) a3f += h2[i] * W5[i];
        out[row] = a3f;
    }
}

extern "C" void kernel_launch(void* const* d_in, const int* in_sizes, int n_in,
                              void* d_out, int out_size, void* d_ws, size_t ws_size,
                              hipStream_t stream) {
    const float* jq = (const float*)d_in[0];
    const float* Kg = (const float*)d_in[1];
    const float* Vg = (const float*)d_in[2];
    const int* mask = (const int*)d_in[3];
    const float* W1 = (const float*)d_in[4];
    const float* b1 = (const float*)d_in[5];
    const float* W2 = (const float*)d_in[6];
    const float* b2 = (const float*)d_in[7];
    const float* W3 = (const float*)d_in[8];
    const float* b3 = (const float*)d_in[9];
    const float* W4 = (const float*)d_in[10];
    const float* b4 = (const float*)d_in[11];
    const float* W5 = (const float*)d_in[12];
    const float* b5 = (const float*)d_in[13];
    float* out = (float*)d_out;

    float* ws = (float*)d_ws;
    float* qenc = ws;                                   // B*J*512 floats
    float* part = qenc + (size_t)BB * JJ * HH * KD;     // B*H*CT*PSTRIDE floats

    enc_kernel<<<BB * JJ, 64, 0, stream>>>(jq, W1, b1, W2, b2, qenc);
    attn_kernel<<<BB * CT, 512, 0, stream>>>(Kg, Vg, mask, qenc, part);
    comb_mlp_kernel<<<BB * JJ, 64, 0, stream>>>(part, W3, b3, W4, b4, W5, b5, out);
}

// Round 17
// 110.046 us; speedup vs baseline: 1.8516x; 1.0632x over previous
//
#include <hip/hip_runtime.h>
#include <hip/hip_bf16.h>

#define BB 64
#define JJ 32
#define NN 4096
#define QD 130
#define KD 128
#define VD 130
#define HH 4
#define CT 4
#define NCH (NN / CT)                 // 1024
#define TIL (NCH / 32)                // 32
#define PSTRIDE (JJ + JJ + JJ * VD)   // 4224 floats per partial block

typedef __attribute__((ext_vector_type(8))) __bf16 bf16x8;
typedef __attribute__((ext_vector_type(4))) float  f32x4;

union FW4 { unsigned int u[4]; bf16x8 v; };

#define SEL_HI 0x07060302u

__device__ __forceinline__ unsigned int packhi(float f0, float f1) {
    return __builtin_amdgcn_perm(__float_as_uint(f1), __float_as_uint(f0), SEL_HI);
}
__device__ __forceinline__ float truncbf(float f) {
    return __uint_as_float(__float_as_uint(f) & 0xFFFF0000u);
}
// truncation split: 8 floats -> hi/lo bf16x8 planes (f = h + l + O(2^-17))
__device__ __forceinline__ void split8(float4 a, float4 b, bf16x8* h, bf16x8* l) {
    FW4 H, L;
    H.u[0] = packhi(a.x, a.y);
    H.u[1] = packhi(a.z, a.w);
    H.u[2] = packhi(b.x, b.y);
    H.u[3] = packhi(b.z, b.w);
    L.u[0] = packhi(a.x - truncbf(a.x), a.y - truncbf(a.y));
    L.u[1] = packhi(a.z - truncbf(a.z), a.w - truncbf(a.w));
    L.u[2] = packhi(b.x - truncbf(b.x), b.y - truncbf(b.y));
    L.u[3] = packhi(b.z - truncbf(b.z), b.w - truncbf(b.w));
    *h = H.v; *l = L.v;
}

// LDS-visibility-only barrier — does NOT drain vmcnt; in-flight global
// register loads survive (compiler inserts counted vmcnt at their consumer).
__device__ __forceinline__ void barrier_novm() {
    __builtin_amdgcn_sched_barrier(0);
    asm volatile("s_waitcnt lgkmcnt(0)" ::: "memory");
    __builtin_amdgcn_s_barrier();
    __builtin_amdgcn_sched_barrier(0);
}

// ---------------------------------------------------------------- encoder ---
__global__ __launch_bounds__(64) void enc_kernel(
        const float* __restrict__ jq,
        const float* __restrict__ W1, const float* __restrict__ b1,
        const float* __restrict__ W2, const float* __restrict__ b2,
        float* __restrict__ qenc) {
    int row = blockIdx.x;          // b*J + j
    int t = threadIdx.x;           // 0..63
    __shared__ float x[QD];
    __shared__ float h[64];
    for (int i = t; i < QD; i += 64) x[i] = jq[row * QD + i];
    __syncthreads();
    float a0 = 0.f, a1 = 0.f;
    for (int i = 0; i < QD - 1; i += 2) {
        a0 += x[i] * W1[i * 64 + t];
        a1 += x[i + 1] * W1[(i + 1) * 64 + t];
    }
    h[t] = fmaxf(b1[t] + a0 + a1, 0.f);
    __syncthreads();
    float a[8];
    #pragma unroll
    for (int s = 0; s < 8; ++s) a[s] = b2[t + 64 * s];
    for (int i = 0; i < 64; ++i) {
        float hv = h[i];
        #pragma unroll
        for (int s = 0; s < 8; ++s) a[s] += hv * W2[i * 512 + t + 64 * s];
    }
    #pragma unroll
    for (int s = 0; s < 8; ++s) qenc[row * 512 + t + 64 * s] = a[s];
}

// -------------------------------------------------------------- attention ---
// Block = (b, chunk of 1024 keys), 512 threads = 8 waves = 4 heads x 2
// q-halves. Skewed T15 pipeline (QK(t) || PV(t-1), softmax in phase 2),
// novm barriers. CONFLICT-FREE STAGING BY CONSTRUCTION: each wave owns one
// (kh,kst) [K] / vc [V] combo, each thread writes LDS slot = its own lane
// -> wave-contiguous b128 writes (2 lanes/bank = free), reads slot = lane
// (free), no padding. The key permutation / V column transpose moved into
// the per-lane GLOBAL source address. Slot contents identical to r13's, so
// frag math, softmax key map, and P-exchange are unchanged.
// (512,2): NEVER force more waves/EU — rounds 4, 9, 15: cap below VGPR+AGPR
// working set -> spill storm (r15: 43% occupancy but 1.7x slower).
__global__ __launch_bounds__(512, 2) void attn_kernel(
        const float* __restrict__ Kg, const float* __restrict__ Vg,
        const int* __restrict__ maskg, const float* __restrict__ qenc,
        float* __restrict__ part) {
    int blk = blockIdx.x;
    int c = blk & (CT - 1);
    int b = blk >> 2;              // CT==4
    int tid = threadIdx.x;
    int wid = tid >> 6;
    int lane = tid & 63;
    int h = wid & 3;               // head
    int qhalf = wid >> 2;          // 0: q 0..15, 1: q 16..31
    int g = lane >> 4;             // lane group 0..3
    int q15 = lane & 15;

    // [dbuf][plane][kh][kst][slot=lane][8]  — 32 KB
    __shared__ __align__(16) __bf16 Kf[2][2][2][4][64][8];
    // [dbuf][plane][vc][slot=lane][8]       — 32 KB
    __shared__ __align__(16) __bf16 Vf[2][2][8][64][8];
    __shared__ float Vt_s[2][2][32];                         // V cols 128,129
    __shared__ int   msks[2][32];

    // ---- staging geometry: slot = lane; wave selects the combo ----
    // K: wave w -> kh = w&1, kst = w>>1. Thread lane: m = lane&15 (mfma row),
    //    chunk = lane>>4. Global key absorbs the permutation:
    //    kh0: key = 8*(m>>2)+(m&3); kh1: key = 8*((m>>2)^2)+4+(m&3).
    int skh = wid & 1, skst = wid >> 1;
    int sm_ = q15;
    int skey = skh ? 8 * ((sm_ >> 2) ^ 2) + 4 + (sm_ & 3)
                   : 8 * (sm_ >> 2) + (sm_ & 3);
    int sd0 = skst * 32 + g * 8;
    // V: wave w -> vc = w. Thread lane: col = vc*16 + (lane&15),
    //    rows = (lane>>4)*8 + j (column gather, 8 strided scalars).
    int svcol = wid * 16 + q15;
    int svrow = g * 8;

    const float* Kb = Kg + (size_t)b * NN * KD;
    const float* Vb = Vg + (size_t)b * NN * VD;
    const int*   Mb = maskg + b * NN;

    float4 kfa, kfb;
    float  vf[8];
    float2 vt = {0.f, 0.f};
    int    mk = 0;

    auto sloadK = [&](int T) {
        int n0 = c * NCH + T * 32;
        const float* ks = Kb + (size_t)(n0 + skey) * KD + sd0;
        kfa = *(const float4*)ks;
        kfb = *(const float4*)(ks + 4);
    };
    auto sloadV = [&](int T) {
        int n0 = c * NCH + T * 32;
        const float* vs = Vb + (size_t)(n0 + svrow) * VD + svcol;
        #pragma unroll
        for (int j = 0; j < 8; ++j) vf[j] = vs[(size_t)j * VD];
        if (tid < 32) {
            vt = *(const float2*)(Vb + (size_t)(n0 + tid) * VD + 128);
            mk = Mb[n0 + tid];
        }
    };
    auto swriteK = [&](int buf) {
        bf16x8 hh, ll;
        split8(kfa, kfb, &hh, &ll);
        *(bf16x8*)&Kf[buf][0][skh][skst][lane][0] = hh;
        *(bf16x8*)&Kf[buf][1][skh][skst][lane][0] = ll;
    };
    auto swriteV = [&](int buf) {
        bf16x8 hh, ll;
        float4 va = {vf[0], vf[1], vf[2], vf[3]};
        float4 vb2 = {vf[4], vf[5], vf[6], vf[7]};
        split8(va, vb2, &hh, &ll);
        *(bf16x8*)&Vf[buf][0][wid][lane][0] = hh;
        *(bf16x8*)&Vf[buf][1][wid][lane][0] = ll;
        if (tid < 32) {
            Vt_s[buf][0][tid] = vt.x;
            Vt_s[buf][1][tid] = vt.y;
            msks[buf][tid] = mk;
        }
    };

    sloadK(0);
    sloadV(0);

    // ---- Q B-frags (hi/lo): lane holds Q[d=kst*32+g*8+j][q=qhalf*16+q15]
    bf16x8 qh[4], ql[4];
    {
        const float* qrow = qenc + (size_t)(b * JJ + qhalf * 16 + q15) * 512
                            + h * KD + g * 8;
        #pragma unroll
        for (int kst = 0; kst < 4; ++kst) {
            float4 qa = *(const float4*)(qrow + kst * 32);
            float4 qb = *(const float4*)(qrow + kst * 32 + 4);
            split8(qa, qb, &qh[kst], &ql[kst]);
        }
    }

    swriteK(0);
    swriteV(0);
    sloadK(1);
    sloadV(1);
    __builtin_amdgcn_sched_barrier(0);

    f32x4 O[8];
    #pragma unroll
    for (int vc = 0; vc < 8; ++vc)
        #pragma unroll
        for (int r = 0; r < 4; ++r) O[vc][r] = 0.f;
    float acct0 = 0.f, acct1 = 0.f;
    float m_run = -1e30f, l_run = 0.f;
    bf16x8 PAH = {}, PAL = {};

    __syncthreads();               // one-time full sync: tile 0 K,V visible

    for (int t = 0; t < TIL; ++t) {
        int cur = t & 1;
        int tpre = (t + 2 < TIL) ? (t + 2) : (TIL - 1);   // clamped prefetch

        // ======== phase 1: QK(t) || PV(t-1) ========
        f32x4 S[2];
        #pragma unroll
        for (int kh = 0; kh < 2; ++kh)
            #pragma unroll
            for (int r = 0; r < 4; ++r) S[kh][r] = 0.f;
        #pragma unroll
        for (int kst = 0; kst < 4; ++kst) {
            #pragma unroll
            for (int kh = 0; kh < 2; ++kh) {
                bf16x8 khf = *(const bf16x8*)&Kf[cur][0][kh][kst][lane][0];
                bf16x8 klf = *(const bf16x8*)&Kf[cur][1][kh][kst][lane][0];
                S[kh] = __builtin_amdgcn_mfma_f32_16x16x32_bf16(khf, qh[kst], S[kh], 0, 0, 0);
                S[kh] = __builtin_amdgcn_mfma_f32_16x16x32_bf16(khf, ql[kst], S[kh], 0, 0, 0);
                S[kh] = __builtin_amdgcn_mfma_f32_16x16x32_bf16(klf, qh[kst], S[kh], 0, 0, 0);
            }
        }
        if (t > 0) {                     // PV(t-1): P(t-1) regs x V(t-1)
            #pragma unroll
            for (int vc = 0; vc < 8; ++vc) {
                bf16x8 vh = *(const bf16x8*)&Vf[cur ^ 1][0][vc][lane][0];
                bf16x8 vl = *(const bf16x8*)&Vf[cur ^ 1][1][vc][lane][0];
                O[vc] = __builtin_amdgcn_mfma_f32_16x16x32_bf16(PAH, vh, O[vc], 0, 0, 0);
                O[vc] = __builtin_amdgcn_mfma_f32_16x16x32_bf16(PAL, vh, O[vc], 0, 0, 0);
                O[vc] = __builtin_amdgcn_mfma_f32_16x16x32_bf16(PAH, vl, O[vc], 0, 0, 0);
            }
        }
        __builtin_amdgcn_sched_barrier(0);
        if (t + 1 < TIL) swriteK((t + 1) & 1);   // counted vmcnt: K(t+1) landed
        sloadK(tpre);                             // K(t+2) issues; flies 1 tile
        barrier_novm();            // bar1: LDS visible, loads stay in flight

        // ======== phase 2: softmax(t) ========
        unsigned int mword = (unsigned int)__ballot(msks[cur][lane & 31] != 0);
        const float sc = 0.08838834764831845f;
        float sp[8];
        float rm = -1e30f;
        #pragma unroll
        for (int r = 0; r < 4; ++r) {
            int key0 = 8 * g + r;
            float s0 = ((mword >> key0) & 1u) ? -1e30f : S[0][r] * sc;
            sp[r] = s0;
            rm = fmaxf(rm, s0);
            int key1 = 8 * (g ^ 2) + 4 + r;
            float s1 = ((mword >> key1) & 1u) ? -1e30f : S[1][r] * sc;
            sp[4 + r] = s1;
            rm = fmaxf(rm, s1);
        }
        rm = fmaxf(rm, __shfl_xor(rm, 16));
        rm = fmaxf(rm, __shfl_xor(rm, 32));
        if (!__all(rm <= m_run + 8.f)) {          // T13 defer-max
            float mn = fmaxf(m_run, rm);
            float rs = __expf(m_run - mn);
            m_run = mn;
            l_run *= rs; acct0 *= rs; acct1 *= rs;
            #pragma unroll
            for (int r = 0; r < 4; ++r) {
                float rr = __shfl(rs, g * 4 + r);  // rare path
                #pragma unroll
                for (int vc = 0; vc < 8; ++vc) O[vc][r] *= rr;
            }
        }
        float ps = 0.f;
        #pragma unroll
        for (int i = 0; i < 8; ++i) {
            float p = __expf(sp[i] - m_run);       // bounded by e^8
            sp[i] = p;
            ps += p;
        }
        ps += __shfl_xor(ps, 16);
        ps += __shfl_xor(ps, 32);
        l_run += ps;

        // fp32 tail: out[q][128|129]
        #pragma unroll
        for (int r = 0; r < 4; ++r) {
            int key0 = 8 * g + r;
            int key1 = 8 * (g ^ 2) + 4 + r;
            acct0 += sp[r] * Vt_s[cur][0][key0] + sp[4 + r] * Vt_s[cur][0][key1];
            acct1 += sp[r] * Vt_s[cur][1][key0] + sp[4 + r] * Vt_s[cur][1][key1];
        }

        // P(t) -> PV A-frag: own kh0 words + xor-32 swapped kh1 words
        unsigned w0h = packhi(sp[0], sp[1]), w1h = packhi(sp[2], sp[3]);
        unsigned w2h = packhi(sp[4], sp[5]), w3h = packhi(sp[6], sp[7]);
        unsigned w0l = packhi(sp[0] - truncbf(sp[0]), sp[1] - truncbf(sp[1]));
        unsigned w1l = packhi(sp[2] - truncbf(sp[2]), sp[3] - truncbf(sp[3]));
        unsigned w2l = packhi(sp[4] - truncbf(sp[4]), sp[5] - truncbf(sp[5]));
        unsigned w3l = packhi(sp[6] - truncbf(sp[6]), sp[7] - truncbf(sp[7]));
        FW4 PH, PL;
        PH.u[0] = w0h; PH.u[1] = w1h;
        PH.u[2] = __shfl_xor(w2h, 32);
        PH.u[3] = __shfl_xor(w3h, 32);
        PL.u[0] = w0l; PL.u[1] = w1l;
        PL.u[2] = __shfl_xor(w2l, 32);
        PL.u[3] = __shfl_xor(w3l, 32);
        PAH = PH.v; PAL = PL.v;

        __builtin_amdgcn_sched_barrier(0);
        if (t + 1 < TIL) swriteV((t + 1) & 1);   // counted vmcnt: V(t+1) landed
        sloadV(tpre);                             // V(t+2) issues; flies 1 tile
        barrier_novm();            // bar2: LDS visible, loads stay in flight
    }

    // ---- epilogue: PV(TIL-1)
    {
        int lastb = (TIL - 1) & 1;
        #pragma unroll
        for (int vc = 0; vc < 8; ++vc) {
            bf16x8 vh = *(const bf16x8*)&Vf[lastb][0][vc][lane][0];
            bf16x8 vl = *(const bf16x8*)&Vf[lastb][1][vc][lane][0];
            O[vc] = __builtin_amdgcn_mfma_f32_16x16x32_bf16(PAH, vh, O[vc], 0, 0, 0);
            O[vc] = __builtin_amdgcn_mfma_f32_16x16x32_bf16(PAL, vh, O[vc], 0, 0, 0);
            O[vc] = __builtin_amdgcn_mfma_f32_16x16x32_bf16(PAH, vl, O[vc], 0, 0, 0);
        }
    }

    // ---- write partials (PV C layout: q = g*4+r, v = vc*16+q15)
    float* P = part + (size_t)((b * HH + h) * CT + c) * PSTRIDE;
    if (lane < 16) {
        P[qhalf * 16 + lane] = m_run;
        P[JJ + qhalf * 16 + lane] = l_run;
    }
    float* A = P + 2 * JJ;
    #pragma unroll
    for (int vc = 0; vc < 8; ++vc) {
        #pragma unroll
        for (int r = 0; r < 4; ++r) {
            int q = qhalf * 16 + g * 4 + r;
            A[q * VD + vc * 16 + q15] = O[vc][r];
        }
    }
    acct0 += __shfl_xor(acct0, 16);
    acct0 += __shfl_xor(acct0, 32);
    acct1 += __shfl_xor(acct1, 16);
    acct1 += __shfl_xor(acct1, 32);
    if (lane < 16) {
        A[(qhalf * 16 + lane) * VD + 128] = acct0;
        A[(qhalf * 16 + lane) * VD + 129] = acct1;
    }
}

// -------------------------------------------- fused combine + output MLP ----
__global__ __launch_bounds__(64) void comb_mlp_kernel(
        const float* __restrict__ part,
        const float* __restrict__ W3, const float* __restrict__ b3,
        const float* __restrict__ W4, const float* __restrict__ b4,
        const float* __restrict__ W5, const float* __restrict__ b5,
        float* __restrict__ out) {
    int row = blockIdx.x;          // b*J + j
    int b = row >> 5;
    int j = row & 31;
    int t = threadIdx.x;
    __shared__ float w_s[HH][CT];
    __shared__ float x[HH * VD];
    __shared__ float h1[64];
    __shared__ float h2[32];

    if (t < HH * CT) {             // 16 threads
        int h = t / CT, cc = t % CT;
        const float* P = part + (size_t)((b * HH + h) * CT + cc) * PSTRIDE;
        float m = P[j];
        float l = P[JJ + j];
        float mm = m;
        #pragma unroll
        for (int s = 1; s < CT; s <<= 1) mm = fmaxf(mm, __shfl_xor(mm, s));
        float e = __expf(m - mm);
        float L = l * e;
        #pragma unroll
        for (int s = 1; s < CT; s <<= 1) L += __shfl_xor(L, s);
        w_s[h][cc] = (L > 0.f) ? e / L : 0.f;
    }
    __syncthreads();

    for (int idx = t; idx < HH * VD; idx += 64) {
        int h = idx / VD, v = idx - h * VD;
        const float* A = part + (size_t)(b * HH + h) * CT * PSTRIDE + 2 * JJ + j * VD + v;
        float o = 0.f;
        #pragma unroll
        for (int cc = 0; cc < CT; ++cc) o += w_s[h][cc] * A[(size_t)cc * PSTRIDE];
        x[idx] = o;
    }
    __syncthreads();

    float a0 = 0.f, a1 = 0.f, a2 = 0.f, a3 = 0.f;
    for (int i = 0; i < HH * VD; i += 4) {
        a0 += x[i] * W3[i * 64 + t];
        a1 += x[i + 1] * W3[(i + 1) * 64 + t];
        a2 += x[i + 2] * W3[(i + 2) * 64 + t];
        a3 += x[i + 3] * W3[(i + 3) * 64 + t];
    }
    h1[t] = fmaxf(b3[t] + (a0 + a1) + (a2 + a3), 0.f);
    __syncthreads();
    if (t < 32) {
        float c0 = 0.f, c1 = 0.f;
        for (int i = 0; i < 64; i += 2) {
            c0 += h1[i] * W4[i * 32 + t];
            c1 += h1[i + 1] * W4[(i + 1) * 32 + t];
        }
        h2[t] = fmaxf(b4[t] + c0 + c1, 0.f);
    }
    __syncthreads();
    if (t == 0) {
        float a3f = b5[0];
        for (int i = 0; i < 32; ++i) a3f += h2[i] * W5[i];
        out[row] = a3f;
    }
}

extern "C" void kernel_launch(void* const* d_in, const int* in_sizes, int n_in,
                              void* d_out, int out_size, void* d_ws, size_t ws_size,
                              hipStream_t stream) {
    const float* jq = (const float*)d_in[0];
    const float* Kg = (const float*)d_in[1];
    const float* Vg = (const float*)d_in[2];
    const int* mask = (const int*)d_in[3];
    const float* W1 = (const float*)d_in[4];
    const float* b1 = (const float*)d_in[5];
    const float* W2 = (const float*)d_in[6];
    const float* b2 = (const float*)d_in[7];
    const float* W3 = (const float*)d_in[8];
    const float* b3 = (const float*)d_in[9];
    const float* W4 = (const float*)d_in[10];
    const float* b4 = (const float*)d_in[11];
    const float* W5 = (const float*)d_in[12];
    const float* b5 = (const float*)d_in[13];
    float* out = (float*)d_out;

    float* ws = (float*)d_ws;
    float* qenc = ws;                                   // B*J*512 floats
    float* part = qenc + (size_t)BB * JJ * HH * KD;     // B*H*CT*PSTRIDE floats

    enc_kernel<<<BB * JJ, 64, 0, stream>>>(jq, W1, b1, W2, b2, qenc);
    attn_kernel<<<BB * CT, 512, 0, stream>>>(Kg, Vg, mask, qenc, part);
    comb_mlp_kernel<<<BB * JJ, 64, 0, stream>>>(part, W3, b3, W4, b4, W5, b5, out);
}